// Round 3
// baseline (1484.696 us; speedup 1.0000x reference)
//
#include <hip/hip_runtime.h>
#include <math.h>

// Problem constants (fixed by setup_inputs)
constexpr int B  = 8;
constexpr int D  = 512;
constexpr int T  = 4096;
constexpr int N  = 9;
constexpr int CS = 1024;
constexpr int CD = 8;

constexpr int TT = 8;          // columns (t) per block
constexpr int RP = 518;        // res2 row pitch in doubles (16B-aligned rows, bank-spread)

#define WN_EPS 1e-12

// ---------------- workspace layout (doubles) ----------------
// w_in_n  [N][CD][D]   : 36864
// w_out_n [N][D][CD]   : 36864
// cb_n    [N][CS][CD]  : 73728
// cb_sq   [N][CS]      : 9216
// total 156672 doubles = 1.25 MB

__global__ void rvq_prep(const float* __restrict__ in_v,
                         const float* __restrict__ in_g,
                         const float* __restrict__ out_v,
                         const float* __restrict__ out_g,
                         const float* __restrict__ cb,
                         double* __restrict__ ws) {
    double* w_in_n  = ws;
    double* w_out_n = ws + N * CD * D;
    double* cb_n    = ws + 2 * N * CD * D;
    double* cb_sq   = cb_n + N * CS * CD;

    int blk = blockIdx.x;
    int tid = threadIdx.x;

    if (blk == 0) {
        // w_in rows: one thread per (i,k); 72 rows of length 512
        int row = tid;
        if (row < N * CD) {
            const float* v = in_v + (size_t)row * D;
            double s = 0.0;
            for (int j = 0; j < D; ++j) {
                double x = (double)v[j];
                s += x * x;
            }
            double denom = fmax(sqrt(s), WN_EPS);
            double g = (double)in_g[row];
            for (int j = 0; j < D; ++j)
                w_in_n[(size_t)row * D + j] = (g * (double)v[j]) / denom;
        }
    } else if (blk <= 18) {
        // w_out rows: one thread per (i,d); 4608 rows of length 8
        int row = (blk - 1) * 256 + tid;
        if (row < N * D) {
            const float* v = out_v + (size_t)row * CD;
            double s = 0.0;
            #pragma unroll
            for (int k = 0; k < CD; ++k) { double x = (double)v[k]; s += x * x; }
            double denom = fmax(sqrt(s), WN_EPS);
            double g = (double)out_g[row];
            #pragma unroll
            for (int k = 0; k < CD; ++k)
                w_out_n[(size_t)row * CD + k] = (g * (double)v[k]) / denom;
        }
    } else {
        // codebook rows: one thread per (i,c); 9216 rows of length 8
        int row = (blk - 19) * 256 + tid;
        if (row < N * CS) {
            const float* v = cb + (size_t)row * CD;
            double s = 0.0;
            #pragma unroll
            for (int k = 0; k < CD; ++k) { double x = (double)v[k]; s += x * x; }
            double denom = fmax(sqrt(s), WN_EPS);
            double sq = 0.0;
            #pragma unroll
            for (int k = 0; k < CD; ++k) {
                double e = (double)v[k] / denom;
                cb_n[(size_t)row * CD + k] = e;
                sq += e * e;
            }
            cb_sq[row] = sq;
        }
    }
}

__global__ __launch_bounds__(256)
void rvq_main(const float* __restrict__ z,
              const float* __restrict__ in_b,
              const float* __restrict__ out_b,
              const float* __restrict__ cb,
              const double* __restrict__ ws,
              float* __restrict__ out) {
    const double* w_in_n  = ws;
    const double* w_out_n = ws + N * CD * D;
    const double* cb_n    = ws + 2 * N * CD * D;
    const double* cb_sq   = cb_n + N * CS * CD;

    __shared__ double res2[TT][RP];      // residual [col][d], 33.2 KB
    __shared__ double zpart[4][CD][TT];  // in-proj partials
    __shared__ double zeb[CD][TT];       // z_e (with bias)
    __shared__ double encs[CD][TT];      // normalized encodings
    __shared__ double ensq[TT];
    __shared__ double qv[CD][TT];        // straight-through q
    __shared__ double bdist[32][TT];
    __shared__ int    bidx[32][TT];

    const int tid = threadIdx.x;
    const int blk = blockIdx.x;          // 4096 blocks
    const int b   = blk >> 9;            // 512 blocks per batch
    const int t0  = (blk & 511) * TT;

    // I/O + out-proj mapping: c in [0,8), part in [0,32), d = j*32 + part
    const int cio  = tid & 7;
    const int part = tid >> 3;
    // in-proj chain mapping: c2,k2 in [0,8), p2 = wave
    const int c2 = tid & 7;
    const int k2 = (tid >> 3) & 7;
    const int p2 = tid >> 6;

    // ---- initial residual = z ----
    {
        const float* zb = z + (size_t)b * D * T + t0 + cio;
        #pragma unroll
        for (int j = 0; j < 16; ++j) {
            int d = j * 32 + part;
            res2[cio][d] = (double)zb[(size_t)d * T];
        }
    }
    __syncthreads();

    double blockLoss = 0.0;

    float* codes_out = out + (size_t)B * D * T;          // 16777216
    float* lat_out   = codes_out + (size_t)B * N * T;    // +294912

    for (int i = 0; i < N; ++i) {
        const double* Wi = w_in_n  + (size_t)i * CD * D;
        const double* Wo = w_out_n + (size_t)i * D * CD;
        const double* Cn = cb_n    + (size_t)i * CS * CD;
        const double* Cq = cb_sq   + (size_t)i * CS;
        const float*  Cb = cb      + (size_t)i * CS * CD;

        // ---- in-proj: 64 chains (c,k) x 4 partials of 128 ----
        {
            const double* wrow = Wi + (size_t)k2 * D + p2 * 128;
            const double* rr   = &res2[c2][p2 * 128];
            double acc = 0.0;
            #pragma unroll
            for (int j = 0; j < 64; ++j) {
                double2 wv = *(const double2*)&wrow[2 * j];
                double2 rv = *(const double2*)&rr[2 * j];
                acc = fma(wv.x, rv.x, acc);
                acc = fma(wv.y, rv.y, acc);
            }
            zpart[p2][k2][c2] = acc;
        }
        __syncthreads();

        if (tid < 64) {
            int c = tid & 7, k = tid >> 3;
            double zev = ((zpart[0][k][c] + zpart[1][k][c]) + zpart[2][k][c]) + zpart[3][k][c];
            zev += (double)in_b[i * CD + k];
            zeb[k][c] = zev;
            lat_out[((size_t)b * N * CD + (size_t)i * CD + k) * T + t0 + c] = (float)zev;
        }
        __syncthreads();

        // ---- per-column normalize (8 threads) ----
        if (tid < TT) {
            int c = tid;
            double s = 0.0;
            #pragma unroll
            for (int k = 0; k < CD; ++k) { double zv = zeb[k][c]; s += zv * zv; }
            double denom = fmax(sqrt(s), WN_EPS);
            double es = 0.0;
            #pragma unroll
            for (int k = 0; k < CD; ++k) {
                double e = zeb[k][c] / denom;
                encs[k][c] = e;
                es += e * e;
            }
            ensq[c] = es;
        }
        __syncthreads();

        // ---- distance scan: group g scans codes [g*32,(g+1)*32) for col c ----
        {
            const int g = tid >> 3;
            const int c = tid & 7;
            double e[CD];
            #pragma unroll
            for (int k = 0; k < CD; ++k) e[k] = encs[k][c];
            double es = ensq[c];
            double best = INFINITY;
            int    bi   = 0;
            const int c0 = g * (CS / 32);
            for (int cc = 0; cc < CS / 32; ++cc) {
                int cidx = c0 + cc;
                const double2* row = (const double2*)(Cn + (size_t)cidx * CD);
                double2 r0 = row[0], r1 = row[1], r2 = row[2], r3 = row[3];
                double dot = 0.0;
                dot = fma(e[0], r0.x, dot);
                dot = fma(e[1], r0.y, dot);
                dot = fma(e[2], r1.x, dot);
                dot = fma(e[3], r1.y, dot);
                dot = fma(e[4], r2.x, dot);
                dot = fma(e[5], r2.y, dot);
                dot = fma(e[6], r3.x, dot);
                dot = fma(e[7], r3.y, dot);
                double dist = (es - 2.0 * dot) + Cq[cidx];
                if (dist < best) { best = dist; bi = cidx; }  // first-min
            }
            bdist[g][c] = best;
            bidx[g][c]  = bi;
        }
        __syncthreads();

        // ---- merge + gather + straight-through + loss (8 threads) ----
        if (tid < TT) {
            int c = tid;
            double bd = bdist[0][c];
            int bix   = bidx[0][c];
            #pragma unroll
            for (int g = 1; g < 32; ++g) {
                double dd = bdist[g][c];
                if (dd < bd) { bd = dd; bix = bidx[g][c]; }  // ascending g keeps first-min
            }
            codes_out[((size_t)b * N + i) * T + t0 + c] = (float)bix;
            const float* crow = Cb + (size_t)bix * CD;
            double lc = 0.0;
            #pragma unroll
            for (int k = 0; k < CD; ++k) {
                double zv = zeb[k][c];
                double cv = (double)crow[k];
                double df = zv - cv;
                lc += df * df;
                qv[k][c] = zv + (cv - zv);   // z_e + (z_q_i - z_e)
            }
            // reduce across the 8 active lanes (all in wave 0)
            lc += __shfl_xor(lc, 4);
            lc += __shfl_xor(lc, 2);
            lc += __shfl_xor(lc, 1);
            if (tid == 0) blockLoss += lc;
        }
        __syncthreads();

        // ---- out-proj + residual update ----
        {
            double q[CD];
            #pragma unroll
            for (int k = 0; k < CD; ++k) q[k] = qv[k][cio];
            #pragma unroll
            for (int j = 0; j < 16; ++j) {
                int d = j * 32 + part;
                const double2* wr = (const double2*)(Wo + (size_t)d * CD);
                double2 w0 = wr[0], w1 = wr[1], w2 = wr[2], w3 = wr[3];
                double o = 0.0;
                o = fma(w0.x, q[0], o);
                o = fma(w0.y, q[1], o);
                o = fma(w1.x, q[2], o);
                o = fma(w1.y, q[3], o);
                o = fma(w2.x, q[4], o);
                o = fma(w2.y, q[5], o);
                o = fma(w3.x, q[6], o);
                o = fma(w3.y, q[7], o);
                o += (double)out_b[i * D + d];
                res2[cio][d] = res2[cio][d] - o;
            }
        }
        __syncthreads();
    }

    // ---- z_q = z - residual_final ----
    {
        const float* zb = z + (size_t)b * D * T + t0 + cio;
        float* ob = out + (size_t)b * D * T + t0 + cio;
        #pragma unroll
        for (int j = 0; j < 16; ++j) {
            int d = j * 32 + part;
            ob[(size_t)d * T] = (float)((double)zb[(size_t)d * T] - res2[cio][d]);
        }
    }

    // ---- losses (commitment == codebook in forward) ----
    if (tid == 0) {
        float v = (float)(blockLoss * (1.0 / 262144.0));   // / (B*CD*T)
        float* lossp = out + (size_t)B * D * T + (size_t)B * N * T + (size_t)B * N * CD * T;
        atomicAdd(lossp, v);
        atomicAdd(lossp + 1, v);
    }
}

extern "C" void kernel_launch(void* const* d_in, const int* in_sizes, int n_in,
                              void* d_out, int out_size, void* d_ws, size_t ws_size,
                              hipStream_t stream) {
    const float* z     = (const float*)d_in[0];
    const float* in_v  = (const float*)d_in[1];
    const float* in_g  = (const float*)d_in[2];
    const float* in_b  = (const float*)d_in[3];
    const float* out_v = (const float*)d_in[4];
    const float* out_g = (const float*)d_in[5];
    const float* out_b = (const float*)d_in[6];
    const float* cb    = (const float*)d_in[7];
    float* out = (float*)d_out;
    double* ws = (double*)d_ws;

    rvq_prep<<<55, 256, 0, stream>>>(in_v, in_g, out_v, out_g, cb, ws);

    // zero the two loss accumulators (harness poisons d_out; replays don't re-poison)
    float* lossp = out + (size_t)B * D * T + (size_t)B * N * T + (size_t)B * N * CD * T;
    hipMemsetAsync(lossp, 0, 2 * sizeof(float), stream);

    rvq_main<<<4096, 256, 0, stream>>>(z, in_b, out_b, cb, ws, out);
}